// Round 1
// baseline (1205.689 us; speedup 1.0000x reference)
//
#include <hip/hip_runtime.h>
#include <math.h>

// QuantizedAttention: B=2, S=2048, D=1024, H=16, Dh=64.
// Round 0: correct fp32 baseline.
//   ws layout (floats): amax[16] | wq[1M] | wk[1M] | wv[1M] | bq[1k] | bk[1k] | bv[1k]
//                       | qbuf[4M] (also reused as zbuf) | kbuf[4M] | vbuf[4M]
//   total ~63 MB.

typedef __attribute__((ext_vector_type(4))) float f4;

#define E4M3_MAX 448.0f

__global__ void zero16_kernel(float* p) {
  if (threadIdx.x < 16) p[threadIdx.x] = 0.0f;
}

__global__ __launch_bounds__(256) void amax_kernel(const float* __restrict__ src, int n,
                                                   float* __restrict__ dst) {
  float m = 0.0f;
  int stride = gridDim.x * blockDim.x;
  for (int i = blockIdx.x * blockDim.x + threadIdx.x; i < n; i += stride)
    m = fmaxf(m, fabsf(src[i]));
  #pragma unroll
  for (int off = 32; off > 0; off >>= 1)
    m = fmaxf(m, __shfl_xor(m, off));
  __shared__ float wred[4];
  if ((threadIdx.x & 63) == 0) wred[threadIdx.x >> 6] = m;
  __syncthreads();
  if (threadIdx.x == 0) {
    m = fmaxf(fmaxf(wred[0], wred[1]), fmaxf(wred[2], wred[3]));
    // nonnegative floats order like their uint bit patterns
    atomicMax((unsigned int*)dst, __float_as_uint(m));
  }
}

__device__ inline float qdq_e4m3(float w, float amax) {
  float scale = E4M3_MAX / fmaxf(amax, 1e-12f);
  float v = w * scale;
  float a = fmaxf(fabsf(v), 1e-30f);
  int ex;
  (void)frexpf(a, &ex);               // a = m*2^ex, m in [0.5,1) -> floor(log2(a)) = ex-1
  float e = fminf(fmaxf((float)(ex - 1), -6.0f), 8.0f);
  float step = exp2f(e - 3.0f);
  float q = rintf(v / step) * step;   // rintf = round-half-even, matches jnp.round
  q = fminf(fmaxf(q, -E4M3_MAX), E4M3_MAX);
  return q / scale;
}

// W: [H=16][D=1024][Dh=64]  ->  out: [D=1024][H*Dh=1024]  (quant-dequantized)
__global__ __launch_bounds__(256) void quant_repack_kernel(const float* __restrict__ W,
                                                           const float* __restrict__ amaxp,
                                                           float* __restrict__ out) {
  int idx = blockIdx.x * 256 + threadIdx.x;  // 0..1048575
  float amax = *amaxp;
  int e = idx & 63;
  int d = (idx >> 6) & 1023;
  int h = idx >> 16;
  out[d * 1024 + h * 64 + e] = qdq_e4m3(W[idx], amax);
}

__global__ void quant_vec_kernel(const float* __restrict__ b, const float* __restrict__ amaxp,
                                 float* __restrict__ out, int n) {
  int idx = blockIdx.x * blockDim.x + threadIdx.x;
  if (idx < n) out[idx] = qdq_e4m3(b[idx], *amaxp);
}

// C[M,N] = A[M,K] * B[K,N] + bias[N], row-major. 64x64 tile, BK=16, 256 thr, 4x4/thr.
__global__ __launch_bounds__(256) void gemm_bias_kernel(const float* __restrict__ A,
                                                        const float* __restrict__ B,
                                                        const float* __restrict__ bias,
                                                        float* __restrict__ C,
                                                        int M, int N, int K) {
  __shared__ float As[16][68];  // [k][m], pad->16B-aligned f4 rows, 2-way banks (free)
  __shared__ float Bs[16][68];  // [k][n]
  int tid = threadIdx.x;
  int tx = tid & 15, ty = tid >> 4;
  int row0 = blockIdx.y * 64, col0 = blockIdx.x * 64;
  float acc[4][4] = {};
  for (int k0 = 0; k0 < K; k0 += 16) {
    #pragma unroll
    for (int i = 0; i < 4; i++) {
      int idx = tid + i * 256;
      int r = idx >> 4, c = idx & 15;          // A tile: 64 rows x 16 k
      As[c][r] = A[(size_t)(row0 + r) * K + (k0 + c)];
      int rb = idx >> 6, cb = idx & 63;        // B tile: 16 k x 64 cols
      Bs[rb][cb] = B[(size_t)(k0 + rb) * N + (col0 + cb)];
    }
    __syncthreads();
    #pragma unroll
    for (int kk = 0; kk < 16; kk++) {
      f4 a4 = *(const f4*)&As[kk][ty * 4];
      f4 b4 = *(const f4*)&Bs[kk][tx * 4];
      #pragma unroll
      for (int i = 0; i < 4; i++)
        #pragma unroll
        for (int j = 0; j < 4; j++)
          acc[i][j] += a4[i] * b4[j];
    }
    __syncthreads();
  }
  f4 bb = *(const f4*)&bias[col0 + tx * 4];
  #pragma unroll
  for (int i = 0; i < 4; i++) {
    f4 st;
    #pragma unroll
    for (int j = 0; j < 4; j++) st[j] = acc[i][j] + bb[j];
    *(f4*)&C[(size_t)(row0 + ty * 4 + i) * N + (col0 + tx * 4)] = st;
  }
}

// In-place rotary on q and k. One block per (b,s) row; partner value via shfl_xor(lane,32).
__global__ __launch_bounds__(256) void rotary_kernel(float* qb, float* kb) {
  int bs = blockIdx.x;        // b*2048 + s
  int s = bs & 2047;
  int tid = threadIdx.x;
  int e = tid & 63;
  int w = tid >> 6;
  int j = e & 31;
  // inv_freq = 10000^(-j/32) = 2^(-j*log2(10000)/32)
  float inv_freq = exp2f((float)j * (-13.287712379549449f / 32.0f));
  float ang = (float)s * inv_freq;
  float c = cosf(ang);
  float sn = sinf(ang);
  float sgn = (e < 32) ? -1.0f : 1.0f;  // flip = [-x[e+32] | x[e-32]]
  size_t base = (size_t)bs * 1024;
  #pragma unroll
  for (int i = 0; i < 4; i++) {
    int h = w + i * 4;
    size_t idx = base + (size_t)h * 64 + e;
    float x = qb[idx];
    float xp = __shfl_xor(x, 32);
    qb[idx] = x * c + sgn * xp * sn;
    float y = kb[idx];
    float yp = __shfl_xor(y, 32);
    kb[idx] = y * c + sgn * yp * sn;
  }
}

// Causal flash attention, fp32. Block: 256 thr, one 64-row Q tile of one (b,h).
// qb layout [b*S+s][h*64+e]. zb may alias qb (blocks only write their own rows/head-slice,
// which no other block reads). NOTE: no __restrict__ on qb/zb because they alias.
__global__ __launch_bounds__(256) void flash_kernel(const float* qb,
                                                    const float* __restrict__ kb,
                                                    const float* __restrict__ vb,
                                                    float* zb) {
  int qt = blockIdx.x, h = blockIdx.y, b = blockIdx.z;
  int tid = threadIdx.x;
  int tx = tid & 15, ty = tid >> 4;
  __shared__ float Qs[64][68];  // [row][e]
  __shared__ float KV[64][68];  // K phase: [e][kv] (transposed); V phase: [kv][e]
  __shared__ float Ps[64][68];  // [row][kv]
  size_t base_q = ((size_t)(b * 2048 + qt * 64) * 1024) + (size_t)h * 64;
  #pragma unroll
  for (int i = 0; i < 16; i++) {
    int idx = tid + i * 256;
    int r = idx >> 6, e = idx & 63;
    Qs[r][e] = qb[base_q + (size_t)r * 1024 + e];
  }
  float acc[4][4] = {};
  float mrow[4] = {-INFINITY, -INFINITY, -INFINITY, -INFINITY};
  float lrow[4] = {0.0f, 0.0f, 0.0f, 0.0f};

  for (int kt = 0; kt <= qt; kt++) {
    size_t base_k = ((size_t)(b * 2048 + kt * 64) * 1024) + (size_t)h * 64;
    __syncthreads();  // prev PV reads of KV done (also covers initial Qs fill)
    #pragma unroll
    for (int i = 0; i < 16; i++) {
      int idx = tid + i * 256;
      int r = idx >> 6, e = idx & 63;
      KV[e][r] = kb[base_k + (size_t)r * 1024 + e];  // transposed: [e][kv]
    }
    __syncthreads();
    // S = Q*K^T / 8
    float s[4][4] = {};
    #pragma unroll 4
    for (int e4 = 0; e4 < 64; e4 += 4) {
      f4 q4[4];
      #pragma unroll
      for (int i = 0; i < 4; i++) q4[i] = *(const f4*)&Qs[ty * 4 + i][e4];
      #pragma unroll
      for (int u = 0; u < 4; u++) {
        f4 k4 = *(const f4*)&KV[e4 + u][tx * 4];
        #pragma unroll
        for (int i = 0; i < 4; i++)
          #pragma unroll
          for (int jj = 0; jj < 4; jj++)
            s[i][jj] += q4[i][u] * k4[jj];
      }
    }
    #pragma unroll
    for (int i = 0; i < 4; i++)
      #pragma unroll
      for (int jj = 0; jj < 4; jj++)
        s[i][jj] *= 0.125f;
    if (kt == qt) {  // causal mask only on diagonal tile; matches ref's IGNORE=-1000
      #pragma unroll
      for (int i = 0; i < 4; i++)
        #pragma unroll
        for (int jj = 0; jj < 4; jj++)
          if (tx * 4 + jj > ty * 4 + i) s[i][jj] = -1000.0f;
    }
    // online softmax; row groups = 16 lanes sharing ty (within one wave)
    #pragma unroll
    for (int i = 0; i < 4; i++) {
      float tm = fmaxf(fmaxf(s[i][0], s[i][1]), fmaxf(s[i][2], s[i][3]));
      #pragma unroll
      for (int off = 1; off < 16; off <<= 1)
        tm = fmaxf(tm, __shfl_xor(tm, off));
      float mnew = fmaxf(mrow[i], tm);
      float alpha = expf(mrow[i] - mnew);  // exp(-inf)=0 on first tile
      mrow[i] = mnew;
      float rs = 0.0f;
      #pragma unroll
      for (int jj = 0; jj < 4; jj++) {
        float p = expf(s[i][jj] - mnew);
        s[i][jj] = p;
        rs += p;
      }
      #pragma unroll
      for (int off = 1; off < 16; off <<= 1)
        rs += __shfl_xor(rs, off);
      lrow[i] = lrow[i] * alpha + rs;
      #pragma unroll
      for (int jj = 0; jj < 4; jj++) acc[i][jj] *= alpha;
      f4 pw = {s[i][0], s[i][1], s[i][2], s[i][3]};
      *(f4*)&Ps[ty * 4 + i][tx * 4] = pw;
    }
    __syncthreads();  // S-phase reads of KV + Ps writes complete
    #pragma unroll
    for (int i = 0; i < 16; i++) {
      int idx = tid + i * 256;
      int r = idx >> 6, e = idx & 63;
      KV[r][e] = vb[base_k + (size_t)r * 1024 + e];  // [kv][e]
    }
    __syncthreads();
    // O += P * V
    #pragma unroll 4
    for (int c = 0; c < 64; c += 4) {
      f4 p4[4];
      #pragma unroll
      for (int i = 0; i < 4; i++) p4[i] = *(const f4*)&Ps[ty * 4 + i][c];
      #pragma unroll
      for (int u = 0; u < 4; u++) {
        f4 v4 = *(const f4*)&KV[c + u][tx * 4];
        #pragma unroll
        for (int i = 0; i < 4; i++)
          #pragma unroll
          for (int jj = 0; jj < 4; jj++)
            acc[i][jj] += p4[i][u] * v4[jj];
      }
    }
  }
  #pragma unroll
  for (int i = 0; i < 4; i++) {
    float inv = 1.0f / lrow[i];
    f4 st;
    #pragma unroll
    for (int jj = 0; jj < 4; jj++) st[jj] = acc[i][jj] * inv;
    *(f4*)&zb[base_q + (size_t)(ty * 4 + i) * 1024 + (tx * 4)] = st;
  }
}

extern "C" void kernel_launch(void* const* d_in, const int* in_sizes, int n_in,
                              void* d_out, int out_size, void* d_ws, size_t ws_size,
                              hipStream_t stream) {
  const float* Xq  = (const float*)d_in[0];
  const float* Xk  = (const float*)d_in[1];
  const float* Xv  = (const float*)d_in[2];
  const float* W_Q = (const float*)d_in[3];
  const float* W_K = (const float*)d_in[4];
  const float* W_V = (const float*)d_in[5];
  const float* W_O = (const float*)d_in[6];  // (H,Dh,D) flat == row-major [he][d]
  const float* b_Q = (const float*)d_in[7];
  const float* b_K = (const float*)d_in[8];
  const float* b_V = (const float*)d_in[9];
  const float* b_O = (const float*)d_in[10];
  float* out = (float*)d_out;

  float* ws   = (float*)d_ws;
  float* amax = ws;                    // 16 floats
  float* wq   = ws + 16;               // 1024*1024
  float* wk   = wq + 1048576;
  float* wv   = wk + 1048576;
  float* bq   = wv + 1048576;          // 1024
  float* bk   = bq + 1024;
  float* bv   = bk + 1024;
  float* qbuf = bv + 1024;             // 4096*1024
  float* kbuf = qbuf + 4194304;
  float* vbuf = kbuf + 4194304;
  float* zbuf = qbuf;                  // aliased with qbuf (safe; see flash_kernel)

  zero16_kernel<<<1, 64, 0, stream>>>(amax);
  amax_kernel<<<512, 256, 0, stream>>>(W_Q, 1048576, amax + 0);
  amax_kernel<<<512, 256, 0, stream>>>(W_K, 1048576, amax + 1);
  amax_kernel<<<512, 256, 0, stream>>>(W_V, 1048576, amax + 2);
  amax_kernel<<<4, 256, 0, stream>>>(b_Q, 1024, amax + 3);
  amax_kernel<<<4, 256, 0, stream>>>(b_K, 1024, amax + 4);
  amax_kernel<<<4, 256, 0, stream>>>(b_V, 1024, amax + 5);

  quant_repack_kernel<<<4096, 256, 0, stream>>>(W_Q, amax + 0, wq);
  quant_repack_kernel<<<4096, 256, 0, stream>>>(W_K, amax + 1, wk);
  quant_repack_kernel<<<4096, 256, 0, stream>>>(W_V, amax + 2, wv);
  quant_vec_kernel<<<4, 256, 0, stream>>>(b_Q, amax + 3, bq, 1024);
  quant_vec_kernel<<<4, 256, 0, stream>>>(b_K, amax + 4, bk, 1024);
  quant_vec_kernel<<<4, 256, 0, stream>>>(b_V, amax + 5, bv, 1024);

  dim3 ggrid(16, 64);  // (N/64, M/64), M=4096, N=K=1024
  gemm_bias_kernel<<<ggrid, 256, 0, stream>>>(Xq, wq, bq, qbuf, 4096, 1024, 1024);
  gemm_bias_kernel<<<ggrid, 256, 0, stream>>>(Xk, wk, bk, kbuf, 4096, 1024, 1024);
  gemm_bias_kernel<<<ggrid, 256, 0, stream>>>(Xv, wv, bv, vbuf, 4096, 1024, 1024);

  rotary_kernel<<<4096, 256, 0, stream>>>(qbuf, kbuf);

  dim3 fgrid(32, 16, 2);  // (qtile, h, b)
  flash_kernel<<<fgrid, 256, 0, stream>>>(qbuf, kbuf, vbuf, zbuf);

  gemm_bias_kernel<<<ggrid, 256, 0, stream>>>(zbuf, W_O, b_O, out, 4096, 1024, 1024);
}

// Round 2
// 415.002 us; speedup vs baseline: 2.9053x; 2.9053x over previous
//
#include <hip/hip_runtime.h>
#include <math.h>

// QuantizedAttention: B=2, S=2048, D=1024, H=16, Dh=64.
// Round 1: bf16 MFMA for all 4 GEMMs + flash attention.
// Weights kept in quantized-grid domain (exact in bf16); 1/scale folded into epilogue.

typedef __attribute__((ext_vector_type(8))) short bf16x8;   // 8 bf16 = 4 VGPRs
typedef __attribute__((ext_vector_type(4))) float f32x4;
typedef __attribute__((ext_vector_type(4))) float f4;

#define E4M3_MAX 448.0f

__device__ inline float bf2f(ushort u) { return __uint_as_float(((unsigned)u) << 16); }
__device__ inline ushort f2bf(float f) {
  unsigned u = __float_as_uint(f);
  return (ushort)((u + 0x7FFF + ((u >> 16) & 1)) >> 16);  // RNE
}

__global__ void zero16_kernel(float* p) {
  if (threadIdx.x < 16) p[threadIdx.x] = 0.0f;
}

__global__ __launch_bounds__(256) void amax_kernel(const float* __restrict__ src, int n,
                                                   float* __restrict__ dst) {
  float m = 0.0f;
  int stride = gridDim.x * blockDim.x;
  for (int i = blockIdx.x * blockDim.x + threadIdx.x; i < n; i += stride)
    m = fmaxf(m, fabsf(src[i]));
  #pragma unroll
  for (int off = 32; off > 0; off >>= 1)
    m = fmaxf(m, __shfl_xor(m, off));
  __shared__ float wred[4];
  if ((threadIdx.x & 63) == 0) wred[threadIdx.x >> 6] = m;
  __syncthreads();
  if (threadIdx.x == 0) {
    m = fmaxf(fmaxf(wred[0], wred[1]), fmaxf(wred[2], wred[3]));
    atomicMax((unsigned int*)dst, __float_as_uint(m));  // nonneg floats order as uints
  }
}

// Returns the e4m3 GRID value q (no descale). Exactly representable in bf16 (<=5 sig bits).
__device__ inline float qdq_qval(float w, float amax) {
  float scale = E4M3_MAX / fmaxf(amax, 1e-12f);
  float v = w * scale;
  float a = fmaxf(fabsf(v), 1e-30f);
  int ex;
  (void)frexpf(a, &ex);                 // floor(log2(a)) = ex-1
  float e = fminf(fmaxf((float)(ex - 1), -6.0f), 8.0f);
  float step = exp2f(e - 3.0f);
  float q = rintf(v / step) * step;     // round-half-even matches jnp.round
  return fminf(fmaxf(q, -E4M3_MAX), E4M3_MAX);
}

// biases: full dequantized fp32
__global__ void quant_vec_kernel(const float* __restrict__ b, const float* __restrict__ amaxp,
                                 float* __restrict__ out, int n) {
  int idx = blockIdx.x * blockDim.x + threadIdx.x;
  if (idx < n) {
    float amax = *amaxp;
    float q = qdq_qval(b[idx], amax);
    out[idx] = q * (fmaxf(amax, 1e-12f) * (1.0f / E4M3_MAX));
  }
}

// W [H=16][D=1024][Dh=64] fp32 -> Bt [he=1024][d=1024] bf16 grid values. LDS transpose.
__global__ __launch_bounds__(256) void quant_repack_bt(const float* __restrict__ W,
                                                       const float* __restrict__ amaxp,
                                                       ushort* __restrict__ Bt) {
  __shared__ float tile[64][65];
  int d0 = blockIdx.x * 64, hh = blockIdx.y;
  float amax = *amaxp;
  int tid = threadIdx.x;
  int e = tid & 63, dd = tid >> 6;
  #pragma unroll
  for (int p = 0; p < 16; p++)
    tile[dd + p * 4][e] = W[(size_t)hh * 65536 + (size_t)(d0 + dd + p * 4) * 64 + e];
  __syncthreads();
  int d = tid & 63, ee = tid >> 6;
  #pragma unroll
  for (int p = 0; p < 16; p++) {
    int e2 = ee + p * 4;
    Bt[(size_t)(hh * 64 + e2) * 1024 + d0 + d] = f2bf(qdq_qval(tile[d][e2], amax));
  }
}

// W_O [he=1024][d=1024] fp32 -> woT [d][he] bf16
__global__ __launch_bounds__(256) void wo_trans(const float* __restrict__ W,
                                               ushort* __restrict__ Bt) {
  __shared__ float tile[64][65];
  int d0 = blockIdx.x * 64, he0 = blockIdx.y * 64;
  int tid = threadIdx.x;
  int dcol = tid & 63, hr = tid >> 6;
  #pragma unroll
  for (int p = 0; p < 16; p++)
    tile[hr + p * 4][dcol] = W[(size_t)(he0 + hr + p * 4) * 1024 + d0 + dcol];
  __syncthreads();
  int hcol = tid & 63, dr = tid >> 6;
  #pragma unroll
  for (int p = 0; p < 16; p++)
    Bt[(size_t)(d0 + dr + p * 4) * 1024 + he0 + hcol] = f2bf(tile[hcol][dr + p * 4]);
}

// fp32 -> bf16, 4 elems/thread
__global__ __launch_bounds__(256) void f32_to_bf16_kernel(const float* __restrict__ in,
                                                          ushort* __restrict__ out, int n4) {
  int i = blockIdx.x * 256 + threadIdx.x;
  if (i < n4) {
    f4 v = *(const f4*)(in + (size_t)i * 4);
    uint2 o;
    o.x = (unsigned)f2bf(v[0]) | ((unsigned)f2bf(v[1]) << 16);
    o.y = (unsigned)f2bf(v[2]) | ((unsigned)f2bf(v[3]) << 16);
    *(uint2*)(out + (size_t)i * 4) = o;
  }
}

// C = A[M][K] (bf16) x Bt[N][K]^T (bf16) ; epilogue: *s_inv + bias.
// QUANT=1: s_inv=max(amax,1e-12)/448, out bf16. QUANT=0: s_inv=1, out fp32.
// Block: 256 thr / 4 waves, tile 128x128, BK=32; wave -> 64x64 (4x4 frags 16x16).
template <int QUANT>
__global__ __launch_bounds__(256) void gemm_bf16(const ushort* __restrict__ A,
                                                 const ushort* __restrict__ Bt,
                                                 const float* __restrict__ bias,
                                                 const float* __restrict__ amaxp,
                                                 ushort* __restrict__ outb,
                                                 float* __restrict__ outf,
                                                 int M, int N, int K) {
  __shared__ ushort As[128][40];  // +8 pad: row stride 80B -> 2-way banks (free)
  __shared__ ushort Bs[128][40];
  int tid = threadIdx.x;
  int w = tid >> 6, lane = tid & 63, quad = lane >> 4, l16 = lane & 15;
  int wm = w & 1, wn = w >> 1;
  int row0 = blockIdx.y * 128, col0 = blockIdx.x * 128;
  f32x4 acc[4][4] = {};

  for (int k0 = 0; k0 < K; k0 += 32) {
    __syncthreads();
    #pragma unroll
    for (int i = 0; i < 2; i++) {
      int u = tid + i * 256;                 // 512 units of 16B; 4 units/row of 32 bf16
      int r = u >> 2, cb = u & 3;
      *(uint4*)&As[r][cb * 8] = *(const uint4*)&A[(size_t)(row0 + r) * K + k0 + cb * 8];
      *(uint4*)&Bs[r][cb * 8] = *(const uint4*)&Bt[(size_t)(col0 + r) * K + k0 + cb * 8];
    }
    __syncthreads();
    bf16x8 af[4], bfr[4];
    #pragma unroll
    for (int i = 0; i < 4; i++)
      af[i] = *(const bf16x8*)&As[wm * 64 + i * 16 + l16][quad * 8];
    #pragma unroll
    for (int j = 0; j < 4; j++)
      bfr[j] = *(const bf16x8*)&Bs[wn * 64 + j * 16 + l16][quad * 8];
    #pragma unroll
    for (int i = 0; i < 4; i++)
      #pragma unroll
      for (int j = 0; j < 4; j++)
        acc[i][j] = __builtin_amdgcn_mfma_f32_16x16x32_bf16(af[i], bfr[j], acc[i][j], 0, 0, 0);
  }

  float s_inv = 1.0f;
  if (QUANT) s_inv = fmaxf(*amaxp, 1e-12f) * (1.0f / E4M3_MAX);
  #pragma unroll
  for (int j = 0; j < 4; j++) {
    int col = col0 + wn * 64 + j * 16 + l16;
    float bv = bias[col];
    #pragma unroll
    for (int i = 0; i < 4; i++) {
      int row = row0 + wm * 64 + i * 16 + quad * 4;
      #pragma unroll
      for (int r = 0; r < 4; r++) {
        float v = acc[i][j][r] * s_inv + bv;
        if (QUANT) outb[(size_t)(row + r) * N + col] = f2bf(v);
        else       outf[(size_t)(row + r) * N + col] = v;
      }
    }
  }
}

// In-place rotary on bf16 q/k. Partner via shfl_xor(lane,32); full rotary_dim=64.
__global__ __launch_bounds__(256) void rotary_bf(ushort* qb, ushort* kb) {
  int bs = blockIdx.x;
  int s = bs & 2047;
  int tid = threadIdx.x;
  int e = tid & 63, w = tid >> 6;
  int j = e & 31;
  float inv_freq = exp2f((float)j * (-13.287712379549449f / 32.0f));  // 10000^(-j/32)
  float ang = (float)s * inv_freq;
  float c = cosf(ang), sn = sinf(ang);
  float sgn = (e < 32) ? -1.0f : 1.0f;
  size_t base = (size_t)bs * 1024;
  #pragma unroll
  for (int i = 0; i < 4; i++) {
    int h = w + i * 4;
    size_t idx = base + (size_t)h * 64 + e;
    float x = bf2f(qb[idx]);
    float xp = __shfl_xor(x, 32);
    qb[idx] = f2bf(x * c + sgn * xp * sn);
    float y = bf2f(kb[idx]);
    float yp = __shfl_xor(y, 32);
    kb[idx] = f2bf(y * c + sgn * yp * sn);
  }
}

// v [bs][he] bf16 -> vT [(b*16+h)*64+e][s=2048] bf16
__global__ __launch_bounds__(256) void v_trans(const ushort* __restrict__ v,
                                              ushort* __restrict__ vT) {
  __shared__ ushort tile[64][72];
  int s0 = blockIdx.x * 64, h = blockIdx.y, b = blockIdx.z;
  int tid = threadIdx.x;
  int e = tid & 63, sr = tid >> 6;
  #pragma unroll
  for (int p = 0; p < 16; p++)
    tile[sr + p * 4][e] = v[(size_t)(b * 2048 + s0 + sr + p * 4) * 1024 + h * 64 + e];
  __syncthreads();
  int sc = tid & 63, er = tid >> 6;
  #pragma unroll
  for (int p = 0; p < 16; p++)
    vT[(size_t)((b * 16 + h) * 64 + er + p * 4) * 2048 + s0 + sc] = tile[sc][er + p * 4];
}

// Causal flash attention, bf16 MFMA. 256 thr / 4 waves; Q tile 64 rows (16/wave);
// kv tiles of 64. Layout facts (verified, guide §3): A[m=l16][k=quad*8+j],
// B[k=quad*8+j][n=l16], C/D row=quad*4+r col=l16.
__global__ __launch_bounds__(256) void flash_mfma(const ushort* __restrict__ qb,
                                                  const ushort* __restrict__ kb,
                                                  const ushort* __restrict__ vT,
                                                  ushort* __restrict__ zb) {
  int qt = (int)gridDim.x - 1 - (int)blockIdx.x;  // longest blocks first
  int h = blockIdx.y, b = blockIdx.z;
  int tid = threadIdx.x;
  int w = tid >> 6, lane = tid & 63, quad = lane >> 4, l16 = lane & 15;
  __shared__ ushort Ks[64][72];  // [kv][e]   +8 pad (144B stride, 16B-aligned)
  __shared__ ushort Vs[64][72];  // [e][kv]
  __shared__ ushort Ps[64][72];  // [qrow(all waves)][kv]

  int qrow_a = qt * 64 + w * 16 + l16;                     // A-frag row
  size_t qoff = ((size_t)(b * 2048 + qrow_a) * 1024) + h * 64;
  bf16x8 aq0 = *(const bf16x8*)&qb[qoff + quad * 8];
  bf16x8 aq1 = *(const bf16x8*)&qb[qoff + 32 + quad * 8];

  f32x4 accO[4] = {};
  float mrow[4] = {-INFINITY, -INFINITY, -INFINITY, -INFINITY};
  float lrow[4] = {0.0f, 0.0f, 0.0f, 0.0f};
  int qrow_c = qt * 64 + w * 16 + quad * 4;                // C-frag row base (+r)

  for (int kt = 0; kt <= qt; kt++) {
    __syncthreads();  // prev iter's LDS reads done
    #pragma unroll
    for (int i = 0; i < 2; i++) {
      int u = tid + i * 256;             // 512 units of 16B; 8 units/row of 64 bf16
      int r = u >> 3, cb = u & 7;
      *(uint4*)&Ks[r][cb * 8] =
          *(const uint4*)&kb[((size_t)(b * 2048 + kt * 64 + r) * 1024) + h * 64 + cb * 8];
      *(uint4*)&Vs[r][cb * 8] =
          *(const uint4*)&vT[((size_t)((b * 16 + h) * 64 + r) * 2048) + kt * 64 + cb * 8];
    }
    __syncthreads();

    // S = Q K^T  (16 rows x 64 kv per wave)
    f32x4 sc[4] = {};
    #pragma unroll
    for (int nf = 0; nf < 4; nf++) {
      bf16x8 bk0 = *(const bf16x8*)&Ks[nf * 16 + l16][quad * 8];
      bf16x8 bk1 = *(const bf16x8*)&Ks[nf * 16 + l16][32 + quad * 8];
      sc[nf] = __builtin_amdgcn_mfma_f32_16x16x32_bf16(aq0, bk0, sc[nf], 0, 0, 0);
      sc[nf] = __builtin_amdgcn_mfma_f32_16x16x32_bf16(aq1, bk1, sc[nf], 0, 0, 0);
    }

    // online softmax (rows quad*4+r; cols nf*16+l16, reduce across 16 lanes)
    #pragma unroll
    for (int r = 0; r < 4; r++) {
      float sv[4];
      #pragma unroll
      for (int nf = 0; nf < 4; nf++) {
        float x = sc[nf][r] * 0.125f;
        int kidx = kt * 64 + nf * 16 + l16;
        if (kidx > qrow_c + r) x = -1000.0f;   // matches ref IGNORE
        sv[nf] = x;
      }
      float tm = fmaxf(fmaxf(sv[0], sv[1]), fmaxf(sv[2], sv[3]));
      #pragma unroll
      for (int off = 1; off < 16; off <<= 1)
        tm = fmaxf(tm, __shfl_xor(tm, off));
      float mnew = fmaxf(mrow[r], tm);
      float alpha = __expf(mrow[r] - mnew);    // exp(-inf)=0 on first tile
      mrow[r] = mnew;
      float rs = 0.0f;
      #pragma unroll
      for (int nf = 0; nf < 4; nf++) {
        float p = __expf(sv[nf] - mnew);
        rs += p;
        Ps[w * 16 + quad * 4 + r][nf * 16 + l16] = f2bf(p);
      }
      #pragma unroll
      for (int off = 1; off < 16; off <<= 1)
        rs += __shfl_xor(rs, off);
      lrow[r] = lrow[r] * alpha + rs;
      #pragma unroll
      for (int ef = 0; ef < 4; ef++) accO[ef][r] *= alpha;
    }
    __syncthreads();  // P visible

    // O += P V  (P: 16 x 64kv per wave; V from [e][kv] storage)
    bf16x8 ap0 = *(const bf16x8*)&Ps[w * 16 + l16][quad * 8];
    bf16x8 ap1 = *(const bf16x8*)&Ps[w * 16 + l16][32 + quad * 8];
    #pragma unroll
    for (int ef = 0; ef < 4; ef++) {
      bf16x8 bv0 = *(const bf16x8*)&Vs[ef * 16 + l16][quad * 8];
      bf16x8 bv1 = *(const bf16x8*)&Vs[ef * 16 + l16][32 + quad * 8];
      accO[ef] = __builtin_amdgcn_mfma_f32_16x16x32_bf16(ap0, bv0, accO[ef], 0, 0, 0);
      accO[ef] = __builtin_amdgcn_mfma_f32_16x16x32_bf16(ap1, bv1, accO[ef], 0, 0, 0);
    }
  }

  #pragma unroll
  for (int r = 0; r < 4; r++) {
    float inv = 1.0f / lrow[r];
    int row = qrow_c + r;
    size_t o = ((size_t)(b * 2048 + row) * 1024) + h * 64;
    #pragma unroll
    for (int ef = 0; ef < 4; ef++)
      zb[o + ef * 16 + l16] = f2bf(accO[ef][r] * inv);
  }
}

extern "C" void kernel_launch(void* const* d_in, const int* in_sizes, int n_in,
                              void* d_out, int out_size, void* d_ws, size_t ws_size,
                              hipStream_t stream) {
  const float* Xq  = (const float*)d_in[0];
  const float* Xk  = (const float*)d_in[1];
  const float* Xv  = (const float*)d_in[2];
  const float* W_Q = (const float*)d_in[3];
  const float* W_K = (const float*)d_in[4];
  const float* W_V = (const float*)d_in[5];
  const float* W_O = (const float*)d_in[6];  // [he][d] row-major
  const float* b_Q = (const float*)d_in[7];
  const float* b_K = (const float*)d_in[8];
  const float* b_V = (const float*)d_in[9];
  const float* b_O = (const float*)d_in[10];
  float* out = (float*)d_out;

  char* base = (char*)d_ws;
  float*  amax = (float*)(base + 0);                 // 64 B
  float*  bq   = (float*)(base + 4096);
  float*  bk   = (float*)(base + 8192);
  float*  bv   = (float*)(base + 12288);
  ushort* wq   = (ushort*)(base + 16384);            // 2 MB each
  ushort* wk   = (ushort*)(base + 16384 + 2097152);
  ushort* wv   = (ushort*)(base + 16384 + 2u * 2097152);
  ushort* woT  = (ushort*)(base + 16384 + 3u * 2097152);
  ushort* xq   = (ushort*)(base + 8404992);          // 8 MB each
  ushort* xk   = (ushort*)(base + 16793600);
  ushort* xv   = (ushort*)(base + 25182208);
  ushort* qbf  = (ushort*)(base + 33570816);
  ushort* vT   = (ushort*)(base + 41959424);
  ushort* kbf  = xq;   // reuse after gemm_q consumed xq
  ushort* vbf  = xk;   // reuse after gemm_k consumed xk
  ushort* zbf  = xk;   // reuse after v_trans consumed vbf

  zero16_kernel<<<1, 64, 0, stream>>>(amax);
  amax_kernel<<<512, 256, 0, stream>>>(W_Q, 1048576, amax + 0);
  amax_kernel<<<512, 256, 0, stream>>>(W_K, 1048576, amax + 1);
  amax_kernel<<<512, 256, 0, stream>>>(W_V, 1048576, amax + 2);
  amax_kernel<<<4, 256, 0, stream>>>(b_Q, 1024, amax + 3);
  amax_kernel<<<4, 256, 0, stream>>>(b_K, 1024, amax + 4);
  amax_kernel<<<4, 256, 0, stream>>>(b_V, 1024, amax + 5);

  dim3 qgrid(16, 16);
  quant_repack_bt<<<qgrid, 256, 0, stream>>>(W_Q, amax + 0, wq);
  quant_repack_bt<<<qgrid, 256, 0, stream>>>(W_K, amax + 1, wk);
  quant_repack_bt<<<qgrid, 256, 0, stream>>>(W_V, amax + 2, wv);
  quant_vec_kernel<<<4, 256, 0, stream>>>(b_Q, amax + 3, bq, 1024);
  quant_vec_kernel<<<4, 256, 0, stream>>>(b_K, amax + 4, bk, 1024);
  quant_vec_kernel<<<4, 256, 0, stream>>>(b_V, amax + 5, bv, 1024);
  wo_trans<<<qgrid, 256, 0, stream>>>(W_O, woT);

  f32_to_bf16_kernel<<<4096, 256, 0, stream>>>(Xq, xq, 1048576);
  f32_to_bf16_kernel<<<4096, 256, 0, stream>>>(Xk, xk, 1048576);
  f32_to_bf16_kernel<<<4096, 256, 0, stream>>>(Xv, xv, 1048576);

  dim3 ggrid(8, 32);  // N/128, M/128
  gemm_bf16<1><<<ggrid, 256, 0, stream>>>(xq, wq, bq, amax + 0, qbf, nullptr, 4096, 1024, 1024);
  gemm_bf16<1><<<ggrid, 256, 0, stream>>>(xk, wk, bk, amax + 1, kbf, nullptr, 4096, 1024, 1024);
  gemm_bf16<1><<<ggrid, 256, 0, stream>>>(xv, wv, bv, amax + 2, vbf, nullptr, 4096, 1024, 1024);

  rotary_bf<<<4096, 256, 0, stream>>>(qbf, kbf);

  dim3 vgrid(32, 16, 2);
  v_trans<<<vgrid, 256, 0, stream>>>(vbf, vT);

  dim3 fgrid(32, 16, 2);  // (qtile, h, b)
  flash_mfma<<<fgrid, 256, 0, stream>>>(qbf, kbf, vT, zbf);

  gemm_bf16<0><<<ggrid, 256, 0, stream>>>(zbf, woT, b_O, nullptr, nullptr, out, 4096, 1024, 1024);
}

// Round 5
// 329.218 us; speedup vs baseline: 3.6623x; 1.2606x over previous
//
#include <hip/hip_runtime.h>
#include <math.h>

// QuantizedAttention: B=2, S=2048, D=1024, H=16, Dh=64.
// Round 4: ONE-LINE FIX of round-3: cvt3 grid.x was 1024 (converted only 1/4 of
// X tensors, rest stayed 0xAA poison -> q,k ~ 0 -> absmax 1.21 in rounds 2+3).
// X is B*S*D = 4,194,304 elements -> 1,048,576 threads x 4 -> grid.x = 4096.
// Flash v3 (S^T via 32x32x16, in-register softmax, P^T through LDS) unchanged.

typedef __attribute__((ext_vector_type(8))) short bf16x8;   // 8 bf16 = 4 VGPRs
typedef __attribute__((ext_vector_type(16))) float f32x16;
typedef __attribute__((ext_vector_type(4))) float f32x4;
typedef __attribute__((ext_vector_type(4))) float f4;

#define E4M3_MAX 448.0f

__device__ inline float bf2f(ushort u) { return __uint_as_float(((unsigned)u) << 16); }
__device__ inline ushort f2bf(float f) {
  unsigned u = __float_as_uint(f);
  return (ushort)((u + 0x7FFF + ((u >> 16) & 1)) >> 16);  // RNE
}
__device__ inline unsigned pack2bf(float a, float b) {  // round-half-up
  unsigned ua = __float_as_uint(a), ub = __float_as_uint(b);
  return ((ua + 0x8000u) >> 16) | ((ub + 0x8000u) & 0xFFFF0000u);
}

__global__ void zero16_kernel(float* p) {
  if (threadIdx.x < 16) p[threadIdx.x] = 0.0f;
}

// 6 tensors in one launch; y selects. Nonneg-float uint atomicMax.
__global__ __launch_bounds__(256) void amax6_kernel(const float* __restrict__ p0,
                                                    const float* __restrict__ p1,
                                                    const float* __restrict__ p2,
                                                    const float* __restrict__ p3,
                                                    const float* __restrict__ p4,
                                                    const float* __restrict__ p5,
                                                    float* __restrict__ amax) {
  int y = blockIdx.y;
  const float* src = (y == 0) ? p0 : (y == 1) ? p1 : (y == 2) ? p2 : (y == 3) ? p3 : (y == 4) ? p4 : p5;
  int n = (y < 3) ? 1048576 : 1024;
  float m = 0.0f;
  int stride = gridDim.x * 256;
  for (int i = blockIdx.x * 256 + threadIdx.x; i < n; i += stride)
    m = fmaxf(m, fabsf(src[i]));
  #pragma unroll
  for (int off = 32; off > 0; off >>= 1)
    m = fmaxf(m, __shfl_xor(m, off));
  __shared__ float wred[4];
  if ((threadIdx.x & 63) == 0) wred[threadIdx.x >> 6] = m;
  __syncthreads();
  if (threadIdx.x == 0) {
    m = fmaxf(fmaxf(wred[0], wred[1]), fmaxf(wred[2], wred[3]));
    atomicMax((unsigned int*)(amax + y), __float_as_uint(m));
  }
}

// e4m3 GRID value (no descale) -- exactly representable in bf16.
__device__ inline float qdq_qval(float w, float amax) {
  float scale = E4M3_MAX / fmaxf(amax, 1e-12f);
  float v = w * scale;
  float a = fmaxf(fabsf(v), 1e-30f);
  int ex;
  (void)frexpf(a, &ex);                 // floor(log2(a)) = ex-1
  float e = fminf(fmaxf((float)(ex - 1), -6.0f), 8.0f);
  float step = exp2f(e - 3.0f);
  float q = rintf(v / step) * step;     // round-half-even matches jnp.round
  return fminf(fmaxf(q, -E4M3_MAX), E4M3_MAX);
}

// 3 bias vectors, one launch (y selects); writes dequantized fp32.
__global__ void qvec3_kernel(const float* __restrict__ b0, const float* __restrict__ b1,
                             const float* __restrict__ b2, const float* __restrict__ amax,
                             float* __restrict__ o0, float* __restrict__ o1,
                             float* __restrict__ o2) {
  int y = blockIdx.y;
  const float* b = (y == 0) ? b0 : (y == 1) ? b1 : b2;
  float* o = (y == 0) ? o0 : (y == 1) ? o1 : o2;
  float am = amax[3 + y];
  int idx = blockIdx.x * blockDim.x + threadIdx.x;
  if (idx < 1024) {
    float q = qdq_qval(b[idx], am);
    o[idx] = q * (fmaxf(am, 1e-12f) * (1.0f / E4M3_MAX));
  }
}

// W [H=16][D=1024][Dh=64] fp32 -> Bt [he=1024][d=1024] bf16 grid values; z selects.
__global__ __launch_bounds__(256) void quant_repack_bt3(const float* __restrict__ W0,
                                                        const float* __restrict__ W1,
                                                        const float* __restrict__ W2,
                                                        const float* __restrict__ amaxp,
                                                        ushort* __restrict__ o0,
                                                        ushort* __restrict__ o1,
                                                        ushort* __restrict__ o2) {
  int z = blockIdx.z;
  const float* W = (z == 0) ? W0 : (z == 1) ? W1 : W2;
  ushort* Bt = (z == 0) ? o0 : (z == 1) ? o1 : o2;
  float amax = amaxp[z];
  __shared__ float tile[64][65];
  int d0 = blockIdx.x * 64, hh = blockIdx.y;
  int tid = threadIdx.x;
  int e = tid & 63, dd = tid >> 6;
  #pragma unroll
  for (int p = 0; p < 16; p++)
    tile[dd + p * 4][e] = W[(size_t)hh * 65536 + (size_t)(d0 + dd + p * 4) * 64 + e];
  __syncthreads();
  int d = tid & 63, ee = tid >> 6;
  #pragma unroll
  for (int p = 0; p < 16; p++) {
    int e2 = ee + p * 4;
    Bt[(size_t)(hh * 64 + e2) * 1024 + d0 + d] = f2bf(qdq_qval(tile[d][e2], amax));
  }
}

// W_O [he=1024][d=1024] fp32 -> woT [d][he] bf16
__global__ __launch_bounds__(256) void wo_trans(const float* __restrict__ W,
                                               ushort* __restrict__ Bt) {
  __shared__ float tile[64][65];
  int d0 = blockIdx.x * 64, he0 = blockIdx.y * 64;
  int tid = threadIdx.x;
  int dcol = tid & 63, hr = tid >> 6;
  #pragma unroll
  for (int p = 0; p < 16; p++)
    tile[hr + p * 4][dcol] = W[(size_t)(he0 + hr + p * 4) * 1024 + d0 + dcol];
  __syncthreads();
  int hcol = tid & 63, dr = tid >> 6;
  #pragma unroll
  for (int p = 0; p < 16; p++)
    Bt[(size_t)(d0 + dr + p * 4) * 1024 + he0 + hcol] = f2bf(tile[hcol][dr + p * 4]);
}

// fp32 -> bf16, 3 tensors in one launch (y selects), 4 elems/thread.
// X tensors: 4,194,304 elems -> launch grid.x = 4096 (i in [0, 1048576)).
__global__ __launch_bounds__(256) void cvt3_kernel(const float* __restrict__ i0,
                                                   const float* __restrict__ i1,
                                                   const float* __restrict__ i2,
                                                   ushort* __restrict__ o0,
                                                   ushort* __restrict__ o1,
                                                   ushort* __restrict__ o2) {
  int y = blockIdx.y;
  const float* in = (y == 0) ? i0 : (y == 1) ? i1 : i2;
  ushort* out = (y == 0) ? o0 : (y == 1) ? o1 : o2;
  int i = blockIdx.x * 256 + threadIdx.x;
  f4 v = *(const f4*)(in + (size_t)i * 4);
  uint2 o;
  o.x = (unsigned)f2bf(v[0]) | ((unsigned)f2bf(v[1]) << 16);
  o.y = (unsigned)f2bf(v[2]) | ((unsigned)f2bf(v[3]) << 16);
  *(uint2*)(out + (size_t)i * 4) = o;
}

// C = A[M][K] (bf16) x Bt[N][K]^T ; epilogue *s_inv + bias.  (unchanged)
template <int QUANT>
__global__ __launch_bounds__(256) void gemm_bf16(const ushort* __restrict__ A,
                                                 const ushort* __restrict__ Bt,
                                                 const float* __restrict__ bias,
                                                 const float* __restrict__ amaxp,
                                                 ushort* __restrict__ outb,
                                                 float* __restrict__ outf,
                                                 int M, int N, int K) {
  __shared__ ushort As[128][40];
  __shared__ ushort Bs[128][40];
  int tid = threadIdx.x;
  int w = tid >> 6, lane = tid & 63, quad = lane >> 4, l16 = lane & 15;
  int wm = w & 1, wn = w >> 1;
  int row0 = blockIdx.y * 128, col0 = blockIdx.x * 128;
  f32x4 acc[4][4] = {};

  for (int k0 = 0; k0 < K; k0 += 32) {
    __syncthreads();
    #pragma unroll
    for (int i = 0; i < 2; i++) {
      int u = tid + i * 256;
      int r = u >> 2, cb = u & 3;
      *(uint4*)&As[r][cb * 8] = *(const uint4*)&A[(size_t)(row0 + r) * K + k0 + cb * 8];
      *(uint4*)&Bs[r][cb * 8] = *(const uint4*)&Bt[(size_t)(col0 + r) * K + k0 + cb * 8];
    }
    __syncthreads();
    bf16x8 af[4], bfr[4];
    #pragma unroll
    for (int i = 0; i < 4; i++)
      af[i] = *(const bf16x8*)&As[wm * 64 + i * 16 + l16][quad * 8];
    #pragma unroll
    for (int j = 0; j < 4; j++)
      bfr[j] = *(const bf16x8*)&Bs[wn * 64 + j * 16 + l16][quad * 8];
    #pragma unroll
    for (int i = 0; i < 4; i++)
      #pragma unroll
      for (int j = 0; j < 4; j++)
        acc[i][j] = __builtin_amdgcn_mfma_f32_16x16x32_bf16(af[i], bfr[j], acc[i][j], 0, 0, 0);
  }

  float s_inv = 1.0f;
  if (QUANT) s_inv = fmaxf(*amaxp, 1e-12f) * (1.0f / E4M3_MAX);
  #pragma unroll
  for (int j = 0; j < 4; j++) {
    int col = col0 + wn * 64 + j * 16 + l16;
    float bv = bias[col];
    #pragma unroll
    for (int i = 0; i < 4; i++) {
      int row = row0 + wm * 64 + i * 16 + quad * 4;
      #pragma unroll
      for (int r = 0; r < 4; r++) {
        float v = acc[i][j][r] * s_inv + bv;
        if (QUANT) outb[(size_t)(row + r) * N + col] = f2bf(v);
        else       outf[(size_t)(row + r) * N + col] = v;
      }
    }
  }
}

// In-place rotary on bf16 q/k (unchanged).
__global__ __launch_bounds__(256) void rotary_bf(ushort* qb, ushort* kb) {
  int bs = blockIdx.x;
  int s = bs & 2047;
  int tid = threadIdx.x;
  int e = tid & 63, w = tid >> 6;
  int j = e & 31;
  float inv_freq = exp2f((float)j * (-13.287712379549449f / 32.0f));
  float ang = (float)s * inv_freq;
  float c = cosf(ang), sn = sinf(ang);
  float sgn = (e < 32) ? -1.0f : 1.0f;
  size_t base = (size_t)bs * 1024;
  #pragma unroll
  for (int i = 0; i < 4; i++) {
    int h = w + i * 4;
    size_t idx = base + (size_t)h * 64 + e;
    float x = bf2f(qb[idx]);
    float xp = __shfl_xor(x, 32);
    qb[idx] = f2bf(x * c + sgn * xp * sn);
    float y = bf2f(kb[idx]);
    float yp = __shfl_xor(y, 32);
    kb[idx] = f2bf(y * c + sgn * yp * sn);
  }
}

// v [bs][he] bf16 -> vT [(b*16+h)*64+e][s] bf16 (unchanged).
__global__ __launch_bounds__(256) void v_trans(const ushort* __restrict__ v,
                                              ushort* __restrict__ vT) {
  __shared__ ushort tile[64][72];
  int s0 = blockIdx.x * 64, h = blockIdx.y, b = blockIdx.z;
  int tid = threadIdx.x;
  int e = tid & 63, sr = tid >> 6;
  #pragma unroll
  for (int p = 0; p < 16; p++)
    tile[sr + p * 4][e] = v[(size_t)(b * 2048 + s0 + sr + p * 4) * 1024 + h * 64 + e];
  __syncthreads();
  int sc = tid & 63, er = tid >> 6;
  #pragma unroll
  for (int p = 0; p < 16; p++)
    vT[(size_t)((b * 16 + h) * 64 + er + p * 4) * 2048 + s0 + sc] = tile[sc][er + p * 4];
}

// ---- Flash v3: S^T via 32x32x16, in-register softmax, P^T through LDS. ----
// Block: 256 thr / 4 waves; Q tile 128 (32 q per wave); kv tile 64.
__global__ __launch_bounds__(256, 2) void flash_mfma3(const ushort* __restrict__ qb,
                                                      const ushort* __restrict__ kb,
                                                      const ushort* __restrict__ vT,
                                                      ushort* __restrict__ zb) {
  int qt = (int)gridDim.x - 1 - (int)blockIdx.x;  // longest first
  int h = blockIdx.y, b = blockIdx.z;
  int tid = threadIdx.x;
  int w = tid >> 6, lane = tid & 63, h2 = lane >> 5, l31 = lane & 31;
  __shared__ ushort sbuf[8192 + 9216];   // Ks[4096] | Vs[4096] | P2[128][72] (epilogue: Osb)
  ushort* Ks = sbuf;
  ushort* Vs = sbuf + 4096;
  ushort* P2 = sbuf + 8192;

  const int q0 = qt * 128;
  const int qg = q0 + w * 32 + l31;      // this lane's q (column of S^T)
  const int qrow = w * 32 + l31;         // block-local q row in P2
  size_t qbase = ((size_t)(b * 2048 + qg)) * 1024 + (size_t)h * 64;
  bf16x8 qf[4];                          // Q B-frags: slot (h2,j) of chunk ck <- e=16ck+8h2+j
  #pragma unroll
  for (int ck = 0; ck < 4; ck++)
    qf[ck] = *(const bf16x8*)&qb[qbase + ck * 16 + h2 * 8];

  f32x16 accO[2] = {};                   // O^T: rows e (2 frags), col q
  float mrun = -INFINITY, lrun = 0.0f;
  const float CE = 0.125f;               // 1/sqrt(64)

  int ktmax = 2 * qt + 1;
  for (int kt = 0; kt <= ktmax; kt++) {
    __syncthreads();                     // prev iter's LDS reads done
    {
      size_t kbase = ((size_t)(b * 2048 + kt * 64)) * 1024 + (size_t)h * 64;
      size_t vbase = ((size_t)(b * 16 + h)) * 64 * 2048 + kt * 64;
      #pragma unroll
      for (int i = 0; i < 2; i++) {
        int u = tid + i * 256;           // 512 units of 16B for K and V each
        int r = u >> 3, blk = u & 7;
        int swz = (blk ^ (r & 7)) * 8;   // XOR swizzle -> conflict-free b128
        *(uint4*)&Ks[r * 64 + swz] = *(const uint4*)&kb[kbase + (size_t)r * 1024 + blk * 8];
        *(uint4*)&Vs[r * 64 + swz] = *(const uint4*)&vT[vbase + (size_t)r * 2048 + blk * 8];
      }
    }
    __syncthreads();

    bool active = (kt * 64 <= q0 + w * 32 + 31);  // wave-uniform
    if (active) {
      // S^T = K . Q^T   (M=kv 2 frags of 32, K=e in 4 chunks of 16)
      f32x16 sc[2] = {};
      #pragma unroll
      for (int mf = 0; mf < 2; mf++) {
        int row = mf * 32 + l31;
        int s8 = row & 7;
        #pragma unroll
        for (int ck = 0; ck < 4; ck++) {
          bf16x8 ka = *(const bf16x8*)&Ks[row * 64 + (((2 * ck + h2) ^ s8) * 8)];
          sc[mf] = __builtin_amdgcn_mfma_f32_32x32x16_bf16(ka, qf[ck], sc[mf], 0, 0, 0);
        }
      }

      // causal mask (raw domain: -8000 * 0.125 = -1000 matches ref IGNORE)
      if (kt * 64 + 63 > q0 + w * 32) {
        #pragma unroll
        for (int mf = 0; mf < 2; mf++)
          #pragma unroll
          for (int i = 0; i < 16; i++) {
            int kv = kt * 64 + mf * 32 + (i & 3) + 8 * (i >> 2) + 4 * h2;
            sc[mf][i] = (kv > qg) ? -8000.0f : sc[mf][i];
          }
      }

      // online softmax: in-register (32 values/lane) + one xor-32 shuffle
      float tm = sc[0][0];
      #pragma unroll
      for (int i = 1; i < 16; i++) tm = fmaxf(tm, sc[0][i]);
      #pragma unroll
      for (int i = 0; i < 16; i++) tm = fmaxf(tm, sc[1][i]);
      tm = fmaxf(tm, __shfl_xor(tm, 32));
      float mnew = fmaxf(mrun, tm);
      float alpha = __expf((mrun - mnew) * CE);
      float p[2][16];
      float rs = 0.0f;
      #pragma unroll
      for (int mf = 0; mf < 2; mf++)
        #pragma unroll
        for (int i = 0; i < 16; i++) {
          float pv = __expf((sc[mf][i] - mnew) * CE);
          p[mf][i] = pv;
          rs += pv;
        }
      rs += __shfl_xor(rs, 32);
      lrun = lrun * alpha + rs;
      mrun = mnew;
      #pragma unroll
      for (int mf = 0; mf < 2; mf++)
        #pragma unroll
        for (int i = 0; i < 16; i++) accO[mf][i] *= alpha;

      // write P^T -> LDS as P2[q][kv]: lane owns col q=qrow; C-rows give kv runs of 4
      #pragma unroll
      for (int mf = 0; mf < 2; mf++)
        #pragma unroll
        for (int m = 0; m < 4; m++) {
          uint2 w2;
          w2.x = pack2bf(p[mf][4 * m + 0], p[mf][4 * m + 1]);
          w2.y = pack2bf(p[mf][4 * m + 2], p[mf][4 * m + 3]);
          *(uint2*)&P2[qrow * 72 + 32 * mf + 8 * m + 4 * h2] = w2;
        }
    }
    __syncthreads();                     // P2 visible
    if (active) {
      // O^T += V^T . P^T ; B-frag slot (h2,j) of chunk ck <- P2[qrow][16ck+8h2+j]
      #pragma unroll
      for (int ck = 0; ck < 4; ck++) {
        bf16x8 pB = *(const bf16x8*)&P2[qrow * 72 + ck * 16 + h2 * 8];
        #pragma unroll
        for (int mf = 0; mf < 2; mf++) {
          int row = mf * 32 + l31;
          bf16x8 va = *(const bf16x8*)&Vs[row * 64 + (((2 * ck + h2) ^ (row & 7)) * 8)];
          accO[mf] = __builtin_amdgcn_mfma_f32_32x32x16_bf16(va, pB, accO[mf], 0, 0, 0);
        }
      }
    }
  }

  // epilogue: divide by l, transpose O^T->O through LDS (reuse P2), coalesced store
  float inv = 1.0f / lrun;
  __syncthreads();                       // all waves done with P2/Ks/Vs
  ushort* Osb = P2;                      // 128 x 72
  #pragma unroll
  for (int mf = 0; mf < 2; mf++)
    #pragma unroll
    for (int m = 0; m < 4; m++) {
      int e0 = 32 * mf + 8 * m + 4 * h2;
      float a0 = accO[mf][4 * m + 0] * inv, a1 = accO[mf][4 * m + 1] * inv;
      float a2 = accO[mf][4 * m + 2] * inv, a3 = accO[mf][4 * m + 3] * inv;
      *(unsigned*)&Osb[qrow * 72 + e0] = pack2bf(a0, a1);
      *(unsigned*)&Osb[qrow * 72 + e0 + 2] = pack2bf(a2, a3);
    }
  __syncthreads();
  size_t obase = ((size_t)(b * 2048 + q0)) * 1024 + (size_t)h * 64;
  #pragma unroll
  for (int i = 0; i < 4; i++) {
    int u = tid + i * 256;               // 1024 units: 128 rows x 8 blocks
    int r = u >> 3, blk = u & 7;
    *(uint4*)&zb[obase + (size_t)r * 1024 + blk * 8] = *(const uint4*)&Osb[r * 72 + blk * 8];
  }
}

extern "C" void kernel_launch(void* const* d_in, const int* in_sizes, int n_in,
                              void* d_out, int out_size, void* d_ws, size_t ws_size,
                              hipStream_t stream) {
  const float* Xq  = (const float*)d_in[0];
  const float* Xk  = (const float*)d_in[1];
  const float* Xv  = (const float*)d_in[2];
  const float* W_Q = (const float*)d_in[3];
  const float* W_K = (const float*)d_in[4];
  const float* W_V = (const float*)d_in[5];
  const float* W_O = (const float*)d_in[6];
  const float* b_Q = (const float*)d_in[7];
  const float* b_K = (const float*)d_in[8];
  const float* b_V = (const float*)d_in[9];
  const float* b_O = (const float*)d_in[10];
  float* out = (float*)d_out;

  char* base = (char*)d_ws;
  float*  amax = (float*)(base + 0);
  float*  bq   = (float*)(base + 4096);
  float*  bk   = (float*)(base + 8192);
  float*  bv   = (float*)(base + 12288);
  ushort* wq   = (ushort*)(base + 16384);
  ushort* wk   = (ushort*)(base + 16384 + 2097152);
  ushort* wv   = (ushort*)(base + 16384 + 2u * 2097152);
  ushort* woT  = (ushort*)(base + 16384 + 3u * 2097152);
  ushort* xq   = (ushort*)(base + 8404992);
  ushort* xk   = (ushort*)(base + 16793600);
  ushort* xv   = (ushort*)(base + 25182208);
  ushort* qbf  = (ushort*)(base + 33570816);
  ushort* vT   = (ushort*)(base + 41959424);
  ushort* kbf  = xq;   // reuse after gemm_q consumed xq
  ushort* vbf  = xk;   // reuse after gemm_k consumed xk
  ushort* zbf  = xk;   // reuse after v_trans consumed vbf

  zero16_kernel<<<1, 64, 0, stream>>>(amax);
  dim3 agrid(64, 6);
  amax6_kernel<<<agrid, 256, 0, stream>>>(W_Q, W_K, W_V, b_Q, b_K, b_V, amax);

  dim3 rgrid(16, 16, 3);
  quant_repack_bt3<<<rgrid, 256, 0, stream>>>(W_Q, W_K, W_V, amax, wq, wk, wv);
  dim3 qvgrid(4, 3);
  qvec3_kernel<<<qvgrid, 256, 0, stream>>>(b_Q, b_K, b_V, amax, bq, bk, bv);
  dim3 wgrid(16, 16);
  wo_trans<<<wgrid, 256, 0, stream>>>(W_O, woT);
  dim3 cgrid(4096, 3);  // FIX: X has 4,194,304 elems -> 1,048,576 threads of 4
  cvt3_kernel<<<cgrid, 256, 0, stream>>>(Xq, Xk, Xv, xq, xk, xv);

  dim3 ggrid(8, 32);
  gemm_bf16<1><<<ggrid, 256, 0, stream>>>(xq, wq, bq, amax + 0, qbf, nullptr, 4096, 1024, 1024);
  gemm_bf16<1><<<ggrid, 256, 0, stream>>>(xk, wk, bk, amax + 1, kbf, nullptr, 4096, 1024, 1024);
  gemm_bf16<1><<<ggrid, 256, 0, stream>>>(xv, wv, bv, amax + 2, vbf, nullptr, 4096, 1024, 1024);

  rotary_bf<<<4096, 256, 0, stream>>>(qbf, kbf);

  dim3 vgrid(32, 16, 2);
  v_trans<<<vgrid, 256, 0, stream>>>(vbf, vT);

  dim3 fgrid(16, 16, 2);  // (qtile of 128, h, b)
  flash_mfma3<<<fgrid, 256, 0, stream>>>(qbf, kbf, vT, zbf);

  gemm_bf16<0><<<ggrid, 256, 0, stream>>>(zbf, woT, b_O, nullptr, nullptr, out, 4096, 1024, 1024);
}

// Round 6
// 276.254 us; speedup vs baseline: 4.3644x; 1.1917x over previous
//
#include <hip/hip_runtime.h>
#include <math.h>

// QuantizedAttention: B=2, S=2048, D=1024, H=16, Dh=64.
// Round 5:
//  - QKV GEMMs batched into ONE dispatch (grid.z=3, 768 blocks ~3/CU; were 3x256=1/CU serial)
//  - GEMM staging via __builtin_amdgcn_global_load_lds width=16 (m97 ladder step), unpadded LDS
//  - WO GEMM: 128x64 tile -> 512 blocks (2/CU)
//  - flash: register prefetch of next K/V tile across the compute phase (hide L2 latency)
//  - ws re-laid out so batched QKV outputs don't alias inputs (56.4 MB total)

typedef __attribute__((ext_vector_type(8))) short bf16x8;   // 8 bf16 = 4 VGPRs
typedef __attribute__((ext_vector_type(16))) float f32x16;
typedef __attribute__((ext_vector_type(4))) float f32x4;
typedef __attribute__((ext_vector_type(4))) float f4;

#define E4M3_MAX 448.0f

__device__ inline float bf2f(ushort u) { return __uint_as_float(((unsigned)u) << 16); }
__device__ inline ushort f2bf(float f) {
  unsigned u = __float_as_uint(f);
  return (ushort)((u + 0x7FFF + ((u >> 16) & 1)) >> 16);  // RNE
}
__device__ inline unsigned pack2bf(float a, float b) {  // round-half-up
  unsigned ua = __float_as_uint(a), ub = __float_as_uint(b);
  return ((ua + 0x8000u) >> 16) | ((ub + 0x8000u) & 0xFFFF0000u);
}

// async 16B global -> LDS (direct-to-shared DMA). LDS dest must be
// wave-uniform base + lane*16 — all call sites below satisfy that.
__device__ __forceinline__ void gll16(const ushort* g, ushort* l) {
  __builtin_amdgcn_global_load_lds(
      (const __attribute__((address_space(1))) unsigned int*)g,
      (__attribute__((address_space(3))) unsigned int*)l, 16, 0, 0);
}

__global__ void zero16_kernel(float* p) {
  if (threadIdx.x < 16) p[threadIdx.x] = 0.0f;
}

// 6 tensors in one launch; y selects. Nonneg-float uint atomicMax.
__global__ __launch_bounds__(256) void amax6_kernel(const float* __restrict__ p0,
                                                    const float* __restrict__ p1,
                                                    const float* __restrict__ p2,
                                                    const float* __restrict__ p3,
                                                    const float* __restrict__ p4,
                                                    const float* __restrict__ p5,
                                                    float* __restrict__ amax) {
  int y = blockIdx.y;
  const float* src = (y == 0) ? p0 : (y == 1) ? p1 : (y == 2) ? p2 : (y == 3) ? p3 : (y == 4) ? p4 : p5;
  int n = (y < 3) ? 1048576 : 1024;
  float m = 0.0f;
  int stride = gridDim.x * 256;
  for (int i = blockIdx.x * 256 + threadIdx.x; i < n; i += stride)
    m = fmaxf(m, fabsf(src[i]));
  #pragma unroll
  for (int off = 32; off > 0; off >>= 1)
    m = fmaxf(m, __shfl_xor(m, off));
  __shared__ float wred[4];
  if ((threadIdx.x & 63) == 0) wred[threadIdx.x >> 6] = m;
  __syncthreads();
  if (threadIdx.x == 0) {
    m = fmaxf(fmaxf(wred[0], wred[1]), fmaxf(wred[2], wred[3]));
    atomicMax((unsigned int*)(amax + y), __float_as_uint(m));
  }
}

// e4m3 GRID value (no descale) -- exactly representable in bf16.
__device__ inline float qdq_qval(float w, float amax) {
  float scale = E4M3_MAX / fmaxf(amax, 1e-12f);
  float v = w * scale;
  float a = fmaxf(fabsf(v), 1e-30f);
  int ex;
  (void)frexpf(a, &ex);                 // floor(log2(a)) = ex-1
  float e = fminf(fmaxf((float)(ex - 1), -6.0f), 8.0f);
  float step = exp2f(e - 3.0f);
  float q = rintf(v / step) * step;     // round-half-even matches jnp.round
  return fminf(fmaxf(q, -E4M3_MAX), E4M3_MAX);
}

// 3 bias vectors, one launch (y selects); writes dequantized fp32.
__global__ void qvec3_kernel(const float* __restrict__ b0, const float* __restrict__ b1,
                             const float* __restrict__ b2, const float* __restrict__ amax,
                             float* __restrict__ o0, float* __restrict__ o1,
                             float* __restrict__ o2) {
  int y = blockIdx.y;
  const float* b = (y == 0) ? b0 : (y == 1) ? b1 : b2;
  float* o = (y == 0) ? o0 : (y == 1) ? o1 : o2;
  float am = amax[3 + y];
  int idx = blockIdx.x * blockDim.x + threadIdx.x;
  if (idx < 1024) {
    float q = qdq_qval(b[idx], am);
    o[idx] = q * (fmaxf(am, 1e-12f) * (1.0f / E4M3_MAX));
  }
}

// W [H=16][D=1024][Dh=64] fp32 -> Bt [he=1024][d=1024] bf16 grid values; z selects.
__global__ __launch_bounds__(256) void quant_repack_bt3(const float* __restrict__ W0,
                                                        const float* __restrict__ W1,
                                                        const float* __restrict__ W2,
                                                        const float* __restrict__ amaxp,
                                                        ushort* __restrict__ o0,
                                                        ushort* __restrict__ o1,
                                                        ushort* __restrict__ o2) {
  int z = blockIdx.z;
  const float* W = (z == 0) ? W0 : (z == 1) ? W1 : W2;
  ushort* Bt = (z == 0) ? o0 : (z == 1) ? o1 : o2;
  float amax = amaxp[z];
  __shared__ float tile[64][65];
  int d0 = blockIdx.x * 64, hh = blockIdx.y;
  int tid = threadIdx.x;
  int e = tid & 63, dd = tid >> 6;
  #pragma unroll
  for (int p = 0; p < 16; p++)
    tile[dd + p * 4][e] = W[(size_t)hh * 65536 + (size_t)(d0 + dd + p * 4) * 64 + e];
  __syncthreads();
  int d = tid & 63, ee = tid >> 6;
  #pragma unroll
  for (int p = 0; p < 16; p++) {
    int e2 = ee + p * 4;
    Bt[(size_t)(hh * 64 + e2) * 1024 + d0 + d] = f2bf(qdq_qval(tile[d][e2], amax));
  }
}

// W_O [he=1024][d=1024] fp32 -> woT [d][he] bf16
__global__ __launch_bounds__(256) void wo_trans(const float* __restrict__ W,
                                               ushort* __restrict__ Bt) {
  __shared__ float tile[64][65];
  int d0 = blockIdx.x * 64, he0 = blockIdx.y * 64;
  int tid = threadIdx.x;
  int dcol = tid & 63, hr = tid >> 6;
  #pragma unroll
  for (int p = 0; p < 16; p++)
    tile[hr + p * 4][dcol] = W[(size_t)(he0 + hr + p * 4) * 1024 + d0 + dcol];
  __syncthreads();
  int hcol = tid & 63, dr = tid >> 6;
  #pragma unroll
  for (int p = 0; p < 16; p++)
    Bt[(size_t)(d0 + dr + p * 4) * 1024 + he0 + hcol] = f2bf(tile[hcol][dr + p * 4]);
}

// fp32 -> bf16, 3 tensors in one launch (y selects), 4 elems/thread. grid.x = 4096.
__global__ __launch_bounds__(256) void cvt3_kernel(const float* __restrict__ i0,
                                                   const float* __restrict__ i1,
                                                   const float* __restrict__ i2,
                                                   ushort* __restrict__ o0,
                                                   ushort* __restrict__ o1,
                                                   ushort* __restrict__ o2) {
  int y = blockIdx.y;
  const float* in = (y == 0) ? i0 : (y == 1) ? i1 : i2;
  ushort* out = (y == 0) ? o0 : (y == 1) ? o1 : o2;
  int i = blockIdx.x * 256 + threadIdx.x;
  f4 v = *(const f4*)(in + (size_t)i * 4);
  uint2 o;
  o.x = (unsigned)f2bf(v[0]) | ((unsigned)f2bf(v[1]) << 16);
  o.y = (unsigned)f2bf(v[2]) | ((unsigned)f2bf(v[3]) << 16);
  *(uint2*)(out + (size_t)i * 4) = o;
}

// GEMM body: C = A[M=4096][K=1024] x Bt[N][K]^T, tile 128 x TN, BK=32, 256 thr.
// m97-style: global_load_lds(16B) into UNPADDED LDS; wave-uniform dest = base+lane*16.
// QUANT=1: out bf16 *s_inv+bias; QUANT=0: out fp32 +bias.
template <int QUANT, int TN>
__device__ __forceinline__ void gemm_body(const ushort* __restrict__ A,
                                          const ushort* __restrict__ Bt,
                                          const float* __restrict__ bias, float s_inv,
                                          ushort* __restrict__ outb, float* __restrict__ outf,
                                          int bx, int by, ushort* As, ushort* Bs) {
  const int K = 1024, N = 1024;
  const int JF = TN / 32;                 // j-frags per wave
  int tid = threadIdx.x;
  int w = tid >> 6, lane = tid & 63, quad = lane >> 4, l16 = lane & 15;
  int wm = w & 1, wn = w >> 1;
  int row0 = by * 128, col0 = bx * TN;
  f32x4 acc[4][4] = {};

  for (int k0 = 0; k0 < K; k0 += 32) {
    __syncthreads();
    {
      int u = tid;                        // A tile: 128x32 = 512 units of 16B
      gll16(&A[(size_t)(row0 + (u >> 2)) * K + k0 + (u & 3) * 8], &As[u * 8]);
      u = tid + 256;
      gll16(&A[(size_t)(row0 + (u >> 2)) * K + k0 + (u & 3) * 8], &As[u * 8]);
      u = tid;                            // B tile: TN x 32 = TN*4 units
      gll16(&Bt[(size_t)(col0 + (u >> 2)) * K + k0 + (u & 3) * 8], &Bs[u * 8]);
      if (TN == 128) {
        u = tid + 256;
        gll16(&Bt[(size_t)(col0 + (u >> 2)) * K + k0 + (u & 3) * 8], &Bs[u * 8]);
      }
    }
    __syncthreads();                      // compiler drains vmcnt before barrier
    bf16x8 af[4], bfr[JF];
    #pragma unroll
    for (int i = 0; i < 4; i++)
      af[i] = *(const bf16x8*)&As[(wm * 64 + i * 16 + l16) * 32 + quad * 8];
    #pragma unroll
    for (int j = 0; j < JF; j++)
      bfr[j] = *(const bf16x8*)&Bs[(wn * (TN / 2) + j * 16 + l16) * 32 + quad * 8];
    #pragma unroll
    for (int i = 0; i < 4; i++)
      #pragma unroll
      for (int j = 0; j < JF; j++)
        acc[i][j] = __builtin_amdgcn_mfma_f32_16x16x32_bf16(af[i], bfr[j], acc[i][j], 0, 0, 0);
  }

  #pragma unroll
  for (int j = 0; j < JF; j++) {
    int col = col0 + wn * (TN / 2) + j * 16 + l16;
    float bv = bias[col];
    #pragma unroll
    for (int i = 0; i < 4; i++) {
      int row = row0 + wm * 64 + i * 16 + quad * 4;
      #pragma unroll
      for (int r = 0; r < 4; r++) {
        float v = acc[i][j][r] * s_inv + bv;
        if (QUANT) outb[(size_t)(row + r) * N + col] = f2bf(v);
        else       outf[(size_t)(row + r) * N + col] = v;
      }
    }
  }
}

// Batched QKV projection: grid (8, 32, 3) = 768 blocks.
__global__ __launch_bounds__(256) void gemm3_qkv(const ushort* __restrict__ xq,
                                                 const ushort* __restrict__ xk,
                                                 const ushort* __restrict__ xv,
                                                 const ushort* __restrict__ wq,
                                                 const ushort* __restrict__ wk,
                                                 const ushort* __restrict__ wv,
                                                 const float* __restrict__ bq,
                                                 const float* __restrict__ bk,
                                                 const float* __restrict__ bv,
                                                 const float* __restrict__ amax,
                                                 ushort* __restrict__ oq,
                                                 ushort* __restrict__ ok,
                                                 ushort* __restrict__ ov) {
  __shared__ ushort As[4096], Bs[4096];
  int z = blockIdx.z;
  const ushort* A  = (z == 0) ? xq : (z == 1) ? xk : xv;
  const ushort* Bt = (z == 0) ? wq : (z == 1) ? wk : wv;
  const float* bias = (z == 0) ? bq : (z == 1) ? bk : bv;
  ushort* out = (z == 0) ? oq : (z == 1) ? ok : ov;
  float s_inv = fmaxf(amax[z], 1e-12f) * (1.0f / E4M3_MAX);
  gemm_body<1, 128>(A, Bt, bias, s_inv, out, nullptr, blockIdx.x, blockIdx.y, As, Bs);
}

// Output projection: 128x64 tile -> grid (16, 32) = 512 blocks (2/CU).
__global__ __launch_bounds__(256) void gemm_wo(const ushort* __restrict__ A,
                                               const ushort* __restrict__ Bt,
                                               const float* __restrict__ bias,
                                               float* __restrict__ out) {
  __shared__ ushort As[4096], Bs[2048];
  gemm_body<0, 64>(A, Bt, bias, 1.0f, nullptr, out, blockIdx.x, blockIdx.y, As, Bs);
}

// In-place rotary on bf16 q/k (unchanged).
__global__ __launch_bounds__(256) void rotary_bf(ushort* qb, ushort* kb) {
  int bs = blockIdx.x;
  int s = bs & 2047;
  int tid = threadIdx.x;
  int e = tid & 63, w = tid >> 6;
  int j = e & 31;
  float inv_freq = exp2f((float)j * (-13.287712379549449f / 32.0f));
  float ang = (float)s * inv_freq;
  float c = cosf(ang), sn = sinf(ang);
  float sgn = (e < 32) ? -1.0f : 1.0f;
  size_t base = (size_t)bs * 1024;
  #pragma unroll
  for (int i = 0; i < 4; i++) {
    int h = w + i * 4;
    size_t idx = base + (size_t)h * 64 + e;
    float x = bf2f(qb[idx]);
    float xp = __shfl_xor(x, 32);
    qb[idx] = f2bf(x * c + sgn * xp * sn);
    float y = bf2f(kb[idx]);
    float yp = __shfl_xor(y, 32);
    kb[idx] = f2bf(y * c + sgn * yp * sn);
  }
}

// v [bs][he] bf16 -> vT [(b*16+h)*64+e][s] bf16 (unchanged).
__global__ __launch_bounds__(256) void v_trans(const ushort* __restrict__ v,
                                              ushort* __restrict__ vT) {
  __shared__ ushort tile[64][72];
  int s0 = blockIdx.x * 64, h = blockIdx.y, b = blockIdx.z;
  int tid = threadIdx.x;
  int e = tid & 63, sr = tid >> 6;
  #pragma unroll
  for (int p = 0; p < 16; p++)
    tile[sr + p * 4][e] = v[(size_t)(b * 2048 + s0 + sr + p * 4) * 1024 + h * 64 + e];
  __syncthreads();
  int sc = tid & 63, er = tid >> 6;
  #pragma unroll
  for (int p = 0; p < 16; p++)
    vT[(size_t)((b * 16 + h) * 64 + er + p * 4) * 2048 + s0 + sc] = tile[sc][er + p * 4];
}

// ---- Flash v4: v3 (verified) + register prefetch of next K/V tile. ----
// Block: 256 thr / 4 waves; Q tile 128 (32 q per wave); kv tile 64.
__global__ __launch_bounds__(256, 2) void flash_mfma4(const ushort* __restrict__ qb,
                                                      const ushort* __restrict__ kb,
                                                      const ushort* __restrict__ vT,
                                                      ushort* __restrict__ zb) {
  int qt = (int)gridDim.x - 1 - (int)blockIdx.x;  // longest first
  int h = blockIdx.y, b = blockIdx.z;
  int tid = threadIdx.x;
  int w = tid >> 6, lane = tid & 63, h2 = lane >> 5, l31 = lane & 31;
  __shared__ ushort sbuf[8192 + 9216];   // Ks[4096] | Vs[4096] | P2[128][72] (epilogue: Osb)
  ushort* Ks = sbuf;
  ushort* Vs = sbuf + 4096;
  ushort* P2 = sbuf + 8192;

  const int q0 = qt * 128;
  const int qg = q0 + w * 32 + l31;      // this lane's q (column of S^T)
  const int qrow = w * 32 + l31;         // block-local q row in P2
  size_t qbase = ((size_t)(b * 2048 + qg)) * 1024 + (size_t)h * 64;
  bf16x8 qf[4];                          // Q B-frags: slot (h2,j) of chunk ck <- e=16ck+8h2+j
  #pragma unroll
  for (int ck = 0; ck < 4; ck++)
    qf[ck] = *(const bf16x8*)&qb[qbase + ck * 16 + h2 * 8];

  f32x16 accO[2] = {};                   // O^T: rows e (2 frags), col q
  float mrun = -INFINITY, lrun = 0.0f;
  const float CE = 0.125f;               // 1/sqrt(64)

  // staging geometry (fixed per thread): unit u -> (row r, 16B chunk c), XOR swizzle
  const int u0 = tid, u1 = tid + 256;
  const int r0 = u0 >> 3, c0 = u0 & 7, r1 = u1 >> 3, c1 = u1 & 7;
  const int sw0 = (c0 ^ (r0 & 7)) * 8, sw1 = (c1 ^ (r1 & 7)) * 8;
  const ushort* ksrc0 = kb + ((size_t)(b * 2048 + r0)) * 1024 + (size_t)h * 64 + c0 * 8;
  const ushort* ksrc1 = kb + ((size_t)(b * 2048 + r1)) * 1024 + (size_t)h * 64 + c1 * 8;
  const ushort* vsrc0 = vT + ((size_t)((b * 16 + h) * 64 + r0)) * 2048 + c0 * 8;
  const ushort* vsrc1 = vT + ((size_t)((b * 16 + h) * 64 + r1)) * 2048 + c1 * 8;

  int ktmax = 2 * qt + 1;
  uint4 kc0 = *(const uint4*)ksrc0;      // prefetch tile 0
  uint4 kc1 = *(const uint4*)ksrc1;
  uint4 vc0 = *(const uint4*)vsrc0;
  uint4 vc1 = *(const uint4*)vsrc1;

  for (int kt = 0; kt <= ktmax; kt++) {
    __syncthreads();                     // prev iter's LDS reads done
    *(uint4*)&Ks[r0 * 64 + sw0] = kc0;
    *(uint4*)&Ks[r1 * 64 + sw1] = kc1;
    *(uint4*)&Vs[r0 * 64 + sw0] = vc0;
    *(uint4*)&Vs[r1 * 64 + sw1] = vc1;
    __syncthreads();
    if (kt < ktmax) {                    // prefetch kt+1; in flight across compute
      kc0 = *(const uint4*)(ksrc0 + (size_t)(kt + 1) * 65536);
      kc1 = *(const uint4*)(ksrc1 + (size_t)(kt + 1) * 65536);
      vc0 = *(const uint4*)(vsrc0 + (kt + 1) * 64);
      vc1 = *(const uint4*)(vsrc1 + (kt + 1) * 64);
    }

    bool active = (kt * 64 <= q0 + w * 32 + 31);  // wave-uniform
    if (active) {
      // S^T = K . Q^T   (M=kv 2 frags of 32, K=e in 4 chunks of 16)
      f32x16 sc[2] = {};
      #pragma unroll
      for (int mf = 0; mf < 2; mf++) {
        int row = mf * 32 + l31;
        int s8 = row & 7;
        #pragma unroll
        for (int ck = 0; ck < 4; ck++) {
          bf16x8 ka = *(const bf16x8*)&Ks[row * 64 + (((2 * ck + h2) ^ s8) * 8)];
          sc[mf] = __builtin_amdgcn_mfma_f32_32x32x16_bf16(ka, qf[ck], sc[mf], 0, 0, 0);
        }
      }

      // causal mask (raw domain: -8000 * 0.125 = -1000 matches ref IGNORE)
      if (kt * 64 + 63 > q0 + w * 32) {
        #pragma unroll
        for (int mf = 0; mf < 2; mf++)
          #pragma unroll
          for (int i = 0; i < 16; i++) {
            int kv = kt * 64 + mf * 32 + (i & 3) + 8 * (i >> 2) + 4 * h2;
            sc[mf][i] = (kv > qg) ? -8000.0f : sc[mf][i];
          }
      }

      // online softmax: in-register (32 values/lane) + one xor-32 shuffle
      float tm = sc[0][0];
      #pragma unroll
      for (int i = 1; i < 16; i++) tm = fmaxf(tm, sc[0][i]);
      #pragma unroll
      for (int i = 0; i < 16; i++) tm = fmaxf(tm, sc[1][i]);
      tm = fmaxf(tm, __shfl_xor(tm, 32));
      float mnew = fmaxf(mrun, tm);
      float alpha = __expf((mrun - mnew) * CE);
      float p[2][16];
      float rs = 0.0f;
      #pragma unroll
      for (int mf = 0; mf < 2; mf++)
        #pragma unroll
        for (int i = 0; i < 16; i++) {
          float pv = __expf((sc[mf][i] - mnew) * CE);
          p[mf][i] = pv;
          rs += pv;
        }
      rs += __shfl_xor(rs, 32);
      lrun = lrun * alpha + rs;
      mrun = mnew;
      #pragma unroll
      for (int mf = 0; mf < 2; mf++)
        #pragma unroll
        for (int i = 0; i < 16; i++) accO[mf][i] *= alpha;

      // write P^T -> LDS as P2[q][kv]: lane owns col q=qrow; C-rows give kv runs of 4
      #pragma unroll
      for (int mf = 0; mf < 2; mf++)
        #pragma unroll
        for (int m = 0; m < 4; m++) {
          uint2 w2;
          w2.x = pack2bf(p[mf][4 * m + 0], p[mf][4 * m + 1]);
          w2.y = pack2bf(p[mf][4 * m + 2], p[mf][4 * m + 3]);
          *(uint2*)&P2[qrow * 72 + 32 * mf + 8 * m + 4 * h2] = w2;
        }
    }
    __syncthreads();                     // P2 visible
    if (active) {
      // O^T += V^T . P^T ; B-frag slot (h2,j) of chunk ck <- P2[qrow][16ck+8h2+j]
      #pragma unroll
      for (int ck = 0; ck < 4; ck++) {
        bf16x8 pB = *(const bf16x8*)&P2[qrow * 72 + ck * 16 + h2 * 8];
        #pragma unroll
        for (int mf = 0; mf < 2; mf++) {
          int row = mf * 32 + l31;
          bf16x8 va = *(const bf16x8*)&Vs[row * 64 + (((2 * ck + h2) ^ (row & 7)) * 8)];
          accO[mf] = __builtin_amdgcn_mfma_f32_32x32x16_bf16(va, pB, accO[mf], 0, 0, 0);
        }
      }
    }
  }

  // epilogue: divide by l, transpose O^T->O through LDS (reuse P2), coalesced store
  float inv = 1.0f / lrun;
  __syncthreads();                       // all waves done with P2/Ks/Vs
  ushort* Osb = P2;                      // 128 x 72
  #pragma unroll
  for (int mf = 0; mf < 2; mf++)
    #pragma unroll
    for (int m = 0; m < 4; m++) {
      int e0 = 32 * mf + 8 * m + 4 * h2;
      float a0 = accO[mf][4 * m + 0] * inv, a1 = accO[mf][4 * m + 1] * inv;
      float a2 = accO[mf][4 * m + 2] * inv, a3 = accO[mf][4 * m + 3] * inv;
      *(unsigned*)&Osb[qrow * 72 + e0] = pack2bf(a0, a1);
      *(unsigned*)&Osb[qrow * 72 + e0 + 2] = pack2bf(a2, a3);
    }
  __syncthreads();
  size_t obase = ((size_t)(b * 2048 + q0)) * 1024 + (size_t)h * 64;
  #pragma unroll
  for (int i = 0; i < 4; i++) {
    int u = tid + i * 256;               // 1024 units: 128 rows x 8 blocks
    int r = u >> 3, blk = u & 7;
    *(uint4*)&zb[obase + (size_t)r * 1024 + blk * 8] = *(const uint4*)&Osb[r * 72 + blk * 8];
  }
}

extern "C" void kernel_launch(void* const* d_in, const int* in_sizes, int n_in,
                              void* d_out, int out_size, void* d_ws, size_t ws_size,
                              hipStream_t stream) {
  const float* Xq  = (const float*)d_in[0];
  const float* Xk  = (const float*)d_in[1];
  const float* Xv  = (const float*)d_in[2];
  const float* W_Q = (const float*)d_in[3];
  const float* W_K = (const float*)d_in[4];
  const float* W_V = (const float*)d_in[5];
  const float* W_O = (const float*)d_in[6];
  const float* b_Q = (const float*)d_in[7];
  const float* b_K = (const float*)d_in[8];
  const float* b_V = (const float*)d_in[9];
  const float* b_O = (const float*)d_in[10];
  float* out = (float*)d_out;

  // ws layout (56.4 MB): amax/bias | weights 8.4MB | xq,xk,xv | qbf,kbf,vbf
  // vT overlays xq (dead after gemm3), zbf overlays xk (dead after gemm3/v_trans).
  char* base = (char*)d_ws;
  float*  amax = (float*)(base + 0);
  float*  bq   = (float*)(base + 4096);
  float*  bk   = (float*)(base + 8192);
  float*  bv   = (float*)(base + 12288);
  ushort* wq   = (ushort*)(base + 16384);
  ushort* wk   = (ushort*)(base + 16384 + 2097152);
  ushort* wv   = (ushort*)(base + 16384 + 2u * 2097152);
  ushort* woT  = (ushort*)(base + 16384 + 3u * 2097152);
  ushort* xq   = (ushort*)(base + 8404992);
  ushort* xk   = (ushort*)(base + 16793600);
  ushort* xv   = (ushort*)(base + 25182208);
  ushort* qbf  = (ushort*)(base + 33570816);
  ushort* kbf  = (ushort*)(base + 41959424);
  ushort* vbf  = (ushort*)(base + 50348032);
  ushort* vT   = xq;   // xq dead after gemm3_qkv
  ushort* zbf  = xk;   // xk dead after gemm3_qkv

  zero16_kernel<<<1, 64, 0, stream>>>(amax);
  dim3 agrid(64, 6);
  amax6_kernel<<<agrid, 256, 0, stream>>>(W_Q, W_K, W_V, b_Q, b_K, b_V, amax);

  dim3 rgrid(16, 16, 3);
  quant_repack_bt3<<<rgrid, 256, 0, stream>>>(W_Q, W_K, W_V, amax, wq, wk, wv);
  dim3 qvgrid(4, 3);
  qvec3_kernel<<<qvgrid, 256, 0, stream>>>(b_Q, b_K, b_V, amax, bq, bk, bv);
  dim3 wgrid(16, 16);
  wo_trans<<<wgrid, 256, 0, stream>>>(W_O, woT);
  dim3 cgrid(4096, 3);
  cvt3_kernel<<<cgrid, 256, 0, stream>>>(Xq, Xk, Xv, xq, xk, xv);

  dim3 g3(8, 32, 3);   // batched QKV: 768 blocks ~3/CU
  gemm3_qkv<<<g3, 256, 0, stream>>>(xq, xk, xv, wq, wk, wv, bq, bk, bv, amax,
                                    qbf, kbf, vbf);

  rotary_bf<<<4096, 256, 0, stream>>>(qbf, kbf);

  dim3 vgrid(32, 16, 2);
  v_trans<<<vgrid, 256, 0, stream>>>(vbf, vT);

  dim3 fgrid(16, 16, 2);  // (qtile of 128, h, b)
  flash_mfma4<<<fgrid, 256, 0, stream>>>(qbf, kbf, vT, zbf);

  dim3 wog(16, 32);    // 128x64 tiles: 512 blocks (2/CU)
  gemm_wo<<<wog, 256, 0, stream>>>(zbf, woT, b_O, out);
}